// Round 2
// baseline (363.959 us; speedup 1.0000x reference)
//
#include <hip/hip_runtime.h>
#include <hip/hip_bf16.h>

typedef __hip_bfloat16 bf16_t;
typedef __attribute__((ext_vector_type(8))) short  s16x8;   // 8 bf16 (4 VGPRs) MFMA operand
typedef __attribute__((ext_vector_type(4))) float  f32x4;   // MFMA accumulator

#define N_ROWS 8192
#define D_DIM  1024

// async global->LDS, 16B per lane; LDS dest is wave-uniform base + lane*16B
#define GLOAD_LDS16(g, l)                                                     \
  __builtin_amdgcn_global_load_lds(                                           \
      (const __attribute__((address_space(1))) void*)(g),                     \
      (__attribute__((address_space(3))) void*)(l), 16, 0, 0)

struct alignas(8) bf16x4_s { bf16_t x, y, z, w; };

// ---------------------------------------------------------------------------
// Kernel 1: per-row L2 normalize (fp32 in) -> bf16 out.  One block per row.
// ---------------------------------------------------------------------------
__global__ void __launch_bounds__(256) normalize_kernel(
    const float* __restrict__ z, bf16_t* __restrict__ out) {
  const int row = blockIdx.x;              // 0 .. 2*N_ROWS-1
  const int t   = threadIdx.x;             // 0 .. 255, 4 floats each
  const float4 v = ((const float4*)(z + (size_t)row * D_DIM))[t];
  float ss = v.x * v.x + v.y * v.y + v.z * v.z + v.w * v.w;
  // wave64 reduce
  for (int off = 32; off; off >>= 1) ss += __shfl_down(ss, off);
  __shared__ float wss[4];
  const int wv = t >> 6, ln = t & 63;
  if (ln == 0) wss[wv] = ss;
  __syncthreads();
  const float rn = rsqrtf(wss[0] + wss[1] + wss[2] + wss[3]);
  bf16x4_s o;
  o.x = __float2bfloat16(v.x * rn);
  o.y = __float2bfloat16(v.y * rn);
  o.z = __float2bfloat16(v.z * rn);
  o.w = __float2bfloat16(v.w * rn);
  ((bf16x4_s*)(out + (size_t)row * D_DIM))[t] = o;
}

// ---------------------------------------------------------------------------
// Kernel 2: fused 128x128-tile NT-GEMM (m = A.B^T, A,B row-major normalized
// bf16) + exp + per-row sum (atomicAdd) + diagonal capture.
// 256 threads = 4 waves in 2x2; each wave owns a 64x64 subtile (4x4 frags of
// 16x16, mfma_f32_16x16x32_bf16, BK=32).
// ---------------------------------------------------------------------------
__global__ void __launch_bounds__(256) simexp_gemm(
    const bf16_t* __restrict__ A, const bf16_t* __restrict__ B,
    float* __restrict__ rowsum, float* __restrict__ pos_sim) {
  constexpr int BK = 32;
  __shared__ bf16_t Alds[128 * BK];   // [row][k] row-major, 8 KiB
  __shared__ bf16_t Blds[128 * BK];   // [col(row-of-B)][k], 8 KiB

  const int t    = threadIdx.x;
  const int w    = t >> 6;            // wave 0..3
  const int lane = t & 63;
  const int wr   = w >> 1, wc = w & 1;
  const int rb   = blockIdx.y, cb = blockIdx.x;
  const int row0 = rb * 128, col0 = cb * 128;

  f32x4 acc[4][4];
#pragma unroll
  for (int m = 0; m < 4; ++m)
#pragma unroll
    for (int n = 0; n < 4; ++n) acc[m][n] = (f32x4){0.f, 0.f, 0.f, 0.f};

  // staging map: linear elem = j*2048 + t*8 ; tile row = linear>>5, col = linear&31
  const int srow = t >> 2;            // 0..63  (j adds 64)
  const int scol = (t & 3) * 8;

  for (int k0 = 0; k0 < D_DIM; k0 += BK) {
#pragma unroll
    for (int j = 0; j < 2; ++j) {
      const int r = srow + j * 64;
      GLOAD_LDS16(&A[(size_t)(row0 + r) * D_DIM + k0 + scol],
                  &Alds[j * 2048 + w * 512]);
      GLOAD_LDS16(&B[(size_t)(col0 + r) * D_DIM + k0 + scol],
                  &Blds[j * 2048 + w * 512]);
    }
    __syncthreads();   // compiler emits vmcnt(0) drain before s_barrier

    s16x8 af[4], bfr[4];
#pragma unroll
    for (int m = 0; m < 4; ++m) {
      const int r = wr * 64 + m * 16 + (lane & 15);
      af[m] = *(const s16x8*)&Alds[r * BK + (lane >> 4) * 8];
    }
#pragma unroll
    for (int n = 0; n < 4; ++n) {
      const int r = wc * 64 + n * 16 + (lane & 15);
      bfr[n] = *(const s16x8*)&Blds[r * BK + (lane >> 4) * 8];
    }
#pragma unroll
    for (int m = 0; m < 4; ++m)
#pragma unroll
      for (int n = 0; n < 4; ++n)
        acc[m][n] = __builtin_amdgcn_mfma_f32_16x16x32_bf16(
            af[m], bfr[n], acc[m][n], 0, 0, 0);
    __syncthreads();
  }

  // ---- epilogue ----
  // diagonal capture (only diagonal blocks can contain i==j)
  if (rb == cb) {
#pragma unroll
    for (int m = 0; m < 4; ++m)
#pragma unroll
      for (int n = 0; n < 4; ++n)
#pragma unroll
        for (int r = 0; r < 4; ++r) {
          const int grow = wr * 64 + m * 16 + (lane >> 4) * 4 + r;
          const int gcol = wc * 64 + n * 16 + (lane & 15);
          if (grow == gcol) pos_sim[row0 + grow] = acc[m][n][r];
        }
  }
  // exp + sum over this wave's 64 cols for each of its 64 rows
  float rs[4][4];   // [m][reg]
#pragma unroll
  for (int m = 0; m < 4; ++m)
#pragma unroll
    for (int r = 0; r < 4; ++r) {
      float s = 0.f;
#pragma unroll
      for (int n = 0; n < 4; ++n) s += __expf(acc[m][n][r]);
      // butterfly over lane bits 0..3 (the col dimension of C/D layout)
      s += __shfl_xor(s, 1);
      s += __shfl_xor(s, 2);
      s += __shfl_xor(s, 4);
      s += __shfl_xor(s, 8);
      rs[m][r] = s;
    }
  if ((lane & 15) == 0) {
#pragma unroll
    for (int m = 0; m < 4; ++m)
#pragma unroll
      for (int r = 0; r < 4; ++r) {
        const int grow = wr * 64 + m * 16 + (lane >> 4) * 4 + r;
        atomicAdd(&rowsum[row0 + grow], rs[m][r]);
      }
  }
}

// ---------------------------------------------------------------------------
// Kernel 3: finalize — p_ij, loss, means.  Single block.
// ---------------------------------------------------------------------------
__global__ void __launch_bounds__(256) finalize_kernel(
    const float* __restrict__ rowsum, const float* __restrict__ pos_sim,
    float* __restrict__ out) {
  const int t = threadIdx.x;
  double lsum = 0.0, psum = 0.0;
  for (int i = t; i < N_ROWS; i += 256) {
    const float ps    = pos_sim[i];
    const float pos   = expf(ps);
    const float denom = rowsum[i] - pos;
    const float p     = pos / denom;
    lsum += (double)(-logf(p) - p * ps);
    psum += (double)p;
  }
  for (int off = 32; off; off >>= 1) {
    lsum += __shfl_down(lsum, off);
    psum += __shfl_down(psum, off);
  }
  __shared__ double sl[4], sp[4];
  const int wv = t >> 6, ln = t & 63;
  if (ln == 0) { sl[wv] = lsum; sp[wv] = psum; }
  __syncthreads();
  if (t == 0) {
    const double L = sl[0] + sl[1] + sl[2] + sl[3];
    const double P = sp[0] + sp[1] + sp[2] + sp[3];
    out[0] = (float)(L / N_ROWS);
    out[1] = (float)(P / N_ROWS);
  }
}

// ---------------------------------------------------------------------------
extern "C" void kernel_launch(void* const* d_in, const int* in_sizes, int n_in,
                              void* d_out, int out_size, void* d_ws,
                              size_t ws_size, hipStream_t stream) {
  const float* z = (const float*)d_in[0];
  float* out = (float*)d_out;

  char* ws = (char*)d_ws;
  bf16_t* AB = (bf16_t*)ws;  // normalized bf16, 2*N*D = 32 MiB
  float* rowsum  = (float*)(ws + (size_t)2 * N_ROWS * D_DIM * sizeof(bf16_t));
  float* pos_sim = rowsum + N_ROWS;

  hipMemsetAsync(rowsum, 0, N_ROWS * sizeof(float), stream);

  normalize_kernel<<<2 * N_ROWS, 256, 0, stream>>>(z, AB);

  bf16_t* Amat = AB;
  bf16_t* Bmat = AB + (size_t)N_ROWS * D_DIM;
  dim3 grid(N_ROWS / 128, N_ROWS / 128);  // (cb, rb) = 64 x 64
  simexp_gemm<<<grid, 256, 0, stream>>>(Amat, Bmat, rowsum, pos_sim);

  finalize_kernel<<<1, 256, 0, stream>>>(rowsum, pos_sim, out);
}

// Round 4
// 240.675 us; speedup vs baseline: 1.5122x; 1.5122x over previous
//
#include <hip/hip_runtime.h>
#include <hip/hip_bf16.h>

typedef __hip_bfloat16 bf16_t;
typedef __attribute__((ext_vector_type(8))) short  s16x8;   // 8 bf16 MFMA operand
typedef __attribute__((ext_vector_type(4))) float  f32x4;   // MFMA accumulator

#define N_ROWS 8192
#define D_DIM  1024

// async global->LDS, 16B/lane; LDS dest = wave-uniform base + lane*16B
#define GLOAD_LDS16(g, l)                                                     \
  __builtin_amdgcn_global_load_lds(                                           \
      (const __attribute__((address_space(1))) void*)(g),                     \
      (__attribute__((address_space(3))) void*)(l), 16, 0, 0)

#define WAITCNT_VM(n) asm volatile("s_waitcnt vmcnt(" #n ")" ::: "memory")

struct alignas(8) bf16x4_s { bf16_t x, y, z, w; };

// ---------------------------------------------------------------------------
// Kernel 1: per-row L2 normalize (fp32 in) -> bf16 out. One block per row.
// Blocks 0..31 also zero the 8192-entry rowsum accumulator (replaces memset).
// ---------------------------------------------------------------------------
__global__ void __launch_bounds__(256) normalize_kernel(
    const float* __restrict__ z, bf16_t* __restrict__ out,
    float* __restrict__ rowsum) {
  const int row = blockIdx.x;
  const int t   = threadIdx.x;
  if (row < 32) rowsum[row * 256 + t] = 0.f;
  const float4 v = ((const float4*)(z + (size_t)row * D_DIM))[t];
  float ss = v.x * v.x + v.y * v.y + v.z * v.z + v.w * v.w;
  for (int off = 32; off; off >>= 1) ss += __shfl_down(ss, off);
  __shared__ float wss[4];
  const int wv = t >> 6, ln = t & 63;
  if (ln == 0) wss[wv] = ss;
  __syncthreads();
  const float rn = rsqrtf(wss[0] + wss[1] + wss[2] + wss[3]);
  bf16x4_s o;
  o.x = __float2bfloat16(v.x * rn);
  o.y = __float2bfloat16(v.y * rn);
  o.z = __float2bfloat16(v.z * rn);
  o.w = __float2bfloat16(v.w * rn);
  ((bf16x4_s*)(out + (size_t)row * D_DIM))[t] = o;
}

// ---------------------------------------------------------------------------
// Kernel 2: 256x256-tile NT-GEMM (m = A.B^T) + exp + row-sum + diag capture.
// 512 threads = 8 waves (2 row-waves x 4 col-waves); wave output = 128x64.
// BK=32, ring-3 LDS buffers (96 KiB): compute kt from buf[kt%3] while
// staging kt+2 into buf[(kt+2)%3]; per-wave s_waitcnt vmcnt(4) at the
// K-tile boundary (counted, never 0 in steady state) + raw s_barrier.
// LDS swizzle: 16B-chunk c' = c ^ ((row>>1)&3), applied on the global
// source during staging (gload_lds writes linearly) and on ds_read addrs.
// ---------------------------------------------------------------------------
__global__ void __launch_bounds__(512, 2) simexp_gemm(
    const bf16_t* __restrict__ A, const bf16_t* __restrict__ B,
    float* __restrict__ rowsum, float* __restrict__ pos_sim) {
  constexpr int BK   = 32;
  constexpr int ABUF = 256 * BK;      // 8192 elems (16 KiB) per A (or B) slab
  constexpr int BUFE = 2 * ABUF;      // one ring slot: A slab + B slab
  __shared__ bf16_t lds[3 * BUFE];    // 96 KiB

  const int t    = threadIdx.x;
  const int w    = t >> 6;            // 0..7
  const int lane = t & 63;
  const int wr   = w >> 2;            // 0..1  -> rows wr*128..+128
  const int wc   = w & 3;             // 0..3  -> cols wc*64..+64
  const int rb   = blockIdx.y, cb = blockIdx.x;
  const int row0 = rb * 256, col0 = cb * 256;

  // --- staging source addressing (pre-swizzled global source, rule 21) ---
  // stage instr i covers LDS linear elems [i*4096 + t*8); row = i*128+(t>>2),
  // phys chunk = t&3; it must hold logical chunk (t&3)^((row>>1)&3).
  const int srow = t >> 2;                                  // 0..127
  const int scol = (((t & 3) ^ ((t >> 3) & 3))) * 8;        // swizzled 16B chunk
  const size_t gA0 = (size_t)(row0 + srow) * D_DIM + scol;
  const size_t gA1 = gA0 + (size_t)128 * D_DIM;
  const size_t gB0 = (size_t)(col0 + srow) * D_DIM + scol;
  const size_t gB1 = gB0 + (size_t)128 * D_DIM;
  const int ldst = w * 512;           // wave-uniform dest base (elems) per instr

#define STAGE_A(dst, k0)                                        \
  do {                                                          \
    GLOAD_LDS16(A + gA0 + (k0), (dst) + ldst);                  \
    GLOAD_LDS16(A + gA1 + (k0), (dst) + 4096 + ldst);           \
  } while (0)
#define STAGE_B(dst, k0)                                        \
  do {                                                          \
    GLOAD_LDS16(B + gB0 + (k0), (dst) + ABUF + ldst);           \
    GLOAD_LDS16(B + gB1 + (k0), (dst) + ABUF + 4096 + ldst);    \
  } while (0)

  // --- fragment read offsets (swizzled, element units) ---
  int offA[8], offB[4];
#pragma unroll
  for (int m = 0; m < 8; ++m) {
    const int r = wr * 128 + m * 16 + (lane & 15);
    offA[m] = r * 32 + (((lane >> 4) ^ ((r >> 1) & 3)) * 8);
  }
#pragma unroll
  for (int n = 0; n < 4; ++n) {
    const int r = wc * 64 + n * 16 + (lane & 15);
    offB[n] = r * 32 + (((lane >> 4) ^ ((r >> 1) & 3)) * 8);
  }

  f32x4 acc[8][4];
#pragma unroll
  for (int m = 0; m < 8; ++m)
#pragma unroll
    for (int n = 0; n < 4; ++n) acc[m][n] = (f32x4){0.f, 0.f, 0.f, 0.f};

  bf16_t* b0 = lds;            // current compute slot
  bf16_t* b1 = lds + BUFE;     // next (landing)
  bf16_t* b2 = lds + 2 * BUFE; // stage target (kt+2)

  // prologue: kt0 -> slot0, kt1 -> slot1 (8 loads); drain kt0 (keep kt1's 4)
  STAGE_A(b0, 0); STAGE_B(b0, 0);
  STAGE_A(b1, BK); STAGE_B(b1, BK);
  WAITCNT_VM(4);
  __builtin_amdgcn_s_barrier();

#pragma unroll 1
  for (int kt = 0; kt < 32; ++kt) {
    const int k0n = (kt + 2) * BK;
    const bf16_t* Ab = b0;
    const bf16_t* Bb = b0 + ABUF;

    // ---- phase 1: issue A-stage, read B + A(lo), 16 MFMA ----
    if (kt < 30) STAGE_A(b2, k0n);
    s16x8 bf[4];
#pragma unroll
    for (int n = 0; n < 4; ++n) bf[n] = *(const s16x8*)&Bb[offB[n]];
    s16x8 af[4];
#pragma unroll
    for (int m = 0; m < 4; ++m) af[m] = *(const s16x8*)&Ab[offA[m]];
    __builtin_amdgcn_s_setprio(1);
#pragma unroll
    for (int m = 0; m < 4; ++m)
#pragma unroll
      for (int n = 0; n < 4; ++n)
        acc[m][n] = __builtin_amdgcn_mfma_f32_16x16x32_bf16(
            af[m], bf[n], acc[m][n], 0, 0, 0);
    __builtin_amdgcn_s_setprio(0);

    // ---- phase 2: issue B-stage, read A(hi), 16 MFMA ----
    if (kt < 30) STAGE_B(b2, k0n);
#pragma unroll
    for (int m = 0; m < 4; ++m) af[m] = *(const s16x8*)&Ab[offA[m + 4]];
    __builtin_amdgcn_s_setprio(1);
#pragma unroll
    for (int m = 0; m < 4; ++m)
#pragma unroll
      for (int n = 0; n < 4; ++n)
        acc[m + 4][n] = __builtin_amdgcn_mfma_f32_16x16x32_bf16(
            af[m], bf[n], acc[m + 4][n], 0, 0, 0);
    __builtin_amdgcn_s_setprio(0);

    // ---- boundary: ensure kt+1 landed (kt+2's 4 loads stay in flight) ----
    if (kt < 30) {
      WAITCNT_VM(4);
      __builtin_amdgcn_s_barrier();
    } else if (kt == 30) {
      WAITCNT_VM(0);
      __builtin_amdgcn_s_barrier();
    }
    bf16_t* tmp = b0; b0 = b1; b1 = b2; b2 = tmp;
  }

  // ---- epilogue ----
  // diagonal capture (independent of the LDS reduction below)
  if (rb == cb) {
#pragma unroll
    for (int m = 0; m < 8; ++m)
#pragma unroll
      for (int n = 0; n < 4; ++n)
#pragma unroll
        for (int r = 0; r < 4; ++r) {
          const int grow = wr * 128 + m * 16 + (lane >> 4) * 4 + r;
          const int gcol = wc * 64 + n * 16 + (lane & 15);
          if (grow == gcol) pos_sim[row0 + grow] = acc[m][n][r];
        }
  }

  __syncthreads();                       // all LDS K-tile reads done; reuse lds
  float* red = (float*)lds;              // [4 wc][256 rows]
#pragma unroll
  for (int m = 0; m < 8; ++m)
#pragma unroll
    for (int r = 0; r < 4; ++r) {
      float s = 0.f;
#pragma unroll
      for (int n = 0; n < 4; ++n) s += __expf(acc[m][n][r]);
      s += __shfl_xor(s, 1);
      s += __shfl_xor(s, 2);
      s += __shfl_xor(s, 4);
      s += __shfl_xor(s, 8);
      if ((lane & 15) == 0) {
        const int row_local = wr * 128 + m * 16 + (lane >> 4) * 4 + r;
        red[wc * 256 + row_local] = s;
      }
    }
  __syncthreads();
  if (t < 256) {
    const float s4 = red[t] + red[256 + t] + red[512 + t] + red[768 + t];
    atomicAdd(&rowsum[row0 + t], s4);
  }
#undef STAGE_A
#undef STAGE_B
}

// ---------------------------------------------------------------------------
// Kernel 3: finalize — p_ij, loss, means. Single block.
// ---------------------------------------------------------------------------
__global__ void __launch_bounds__(256) finalize_kernel(
    const float* __restrict__ rowsum, const float* __restrict__ pos_sim,
    float* __restrict__ out) {
  const int t = threadIdx.x;
  double lsum = 0.0, psum = 0.0;
  for (int i = t; i < N_ROWS; i += 256) {
    const float ps    = pos_sim[i];
    const float pos   = expf(ps);
    const float denom = rowsum[i] - pos;
    const float p     = pos / denom;
    lsum += (double)(-logf(p) - p * ps);
    psum += (double)p;
  }
  for (int off = 32; off; off >>= 1) {
    lsum += __shfl_down(lsum, off);
    psum += __shfl_down(psum, off);
  }
  __shared__ double sl[4], sp[4];
  const int wv = t >> 6, ln = t & 63;
  if (ln == 0) { sl[wv] = lsum; sp[wv] = psum; }
  __syncthreads();
  if (t == 0) {
    const double L = sl[0] + sl[1] + sl[2] + sl[3];
    const double P = sp[0] + sp[1] + sp[2] + sp[3];
    out[0] = (float)(L / N_ROWS);
    out[1] = (float)(P / N_ROWS);
  }
}

// ---------------------------------------------------------------------------
extern "C" void kernel_launch(void* const* d_in, const int* in_sizes, int n_in,
                              void* d_out, int out_size, void* d_ws,
                              size_t ws_size, hipStream_t stream) {
  const float* z = (const float*)d_in[0];
  float* out = (float*)d_out;

  char* ws = (char*)d_ws;
  bf16_t* AB = (bf16_t*)ws;  // normalized bf16, 2*N*D = 32 MiB
  float* rowsum  = (float*)(ws + (size_t)2 * N_ROWS * D_DIM * sizeof(bf16_t));
  float* pos_sim = rowsum + N_ROWS;

  normalize_kernel<<<2 * N_ROWS, 256, 0, stream>>>(z, AB, rowsum);

  bf16_t* Amat = AB;
  bf16_t* Bmat = AB + (size_t)N_ROWS * D_DIM;
  dim3 grid(N_ROWS / 256, N_ROWS / 256);  // (cb, rb) = 32 x 32
  simexp_gemm<<<grid, 512, 0, stream>>>(Amat, Bmat, rowsum, pos_sim);

  finalize_kernel<<<1, 256, 0, stream>>>(rowsum, pos_sim, out);
}